// Round 12
// baseline (275.915 us; speedup 1.0000x reference)
//
#include <hip/hip_runtime.h>

// LSTMClassifier round 11: co-resident desynchronized blocks.
//   grid = 512 blocks x 512 threads (8 waves). Block = 4 batch rows.
//   2 independent blocks per CU (no shared barrier) -> 4 waves/SIMD whose
//   stalls interleave. 1 real cell per lane: batch row b -> M-row 4b, so
//   each kg-group's acc[g][0] is its lane's single real cell; junk M-rows
//   stay exactly 0 (zeroed once, never written).
//   Waves 0-3: L0 tile u: h0(k) = f(h0(k-1))               [k <= 511]
//   Waves 4-7: L1 tile u: h1(k-1) = f(h0(k-1), h1(k-2))    [k >= 1]
//   One s_barrier per iter (within block). XOR-rotated h layout; merged-rcp
//   activations (5 exp2 + 2 rcp per cell); -log2e pre-scaled weights/biases.

typedef _Float16 half8    __attribute__((ext_vector_type(8)));
typedef float    float4_t __attribute__((ext_vector_type(4)));

#define T_STEPS 512
#define SIG_K  (-1.442695040888963f)    // -log2(e)
#define TANH_K (-2.885390081777927f)    // -2*log2(e)

__device__ __forceinline__ int hoff(int slot, int row, int kb, int lo) {
    return slot * 1024 + row * 64 + (((kb + row) & 7) << 3) + lo;
}

// inputs pre-scaled: zi,zf,zo by -log2e; zg by -2log2e. c updated in place.
// returns h = sigmoid(o)*tanh(c'). 5 exp2 + 2 rcp.
__device__ __forceinline__ float lstm_cell(float zi, float zf, float zg, float zo,
                                           float& c) {
    const float ei = __builtin_amdgcn_exp2f(zi);
    const float ef = __builtin_amdgcn_exp2f(zf);
    const float v  = __builtin_amdgcn_exp2f(zg);
    const float eo = __builtin_amdgcn_exp2f(zo);
    const float pi = 1.f + ei, pf = 1.f + ef, pv = 1.f + v, po = 1.f + eo;
    const float A   = pi * pv;
    const float num = fmaf(c, A, (1.f - v) * pf);
    const float cn  = num * __builtin_amdgcn_rcpf(pf * A);
    c = cn;
    const float u = __builtin_amdgcn_exp2f(cn * TANH_K);
    return (1.f - u) * __builtin_amdgcn_rcpf(po * (1.f + u));
}

extern "C" __global__ __launch_bounds__(512, 4)
void lstm2_mfma(const float* __restrict__ x,
                const float* __restrict__ w_ih0, const float* __restrict__ w_hh0,
                const float* __restrict__ b_ih0, const float* __restrict__ b_hh0,
                const float* __restrict__ w_ih1, const float* __restrict__ w_hh1,
                const float* __restrict__ b_ih1, const float* __restrict__ b_hh1,
                const float* __restrict__ w_fc,  const float* __restrict__ b_fc,
                float* __restrict__ out)
{
    __shared__ float    x_lds[T_STEPS][4];     // 8 KB (4 batch rows)
    __shared__ _Float16 bufA[2 * 1024];        // h0, 2 slots, 4 KB
    __shared__ _Float16 bufB[2 * 1024];        // h1, 2 slots, 4 KB
    __shared__ float    hfin[4][68];

    const int tid  = threadIdx.x;
    const int wv   = tid >> 6;          // wave 0..7
    const int lane = tid & 63;
    const int cr   = lane & 15;         // A-row (M-row) / C-col (unit)
    const int kg   = lane >> 4;         // k-group 0..3; lane's batch row = kg
    const int rb   = kg * 4;            // M-row of this lane's cell (4*kg)
    const int b0   = blockIdx.x * 4;    // this block's 4 batch rows
    const bool isL0 = (wv < 4);
    const int u    = wv & 3;            // unit tile 0..3
    const int ucol = u * 16 + cr;       // this lane's unit 0..63
    const int wkb  = 2 * u + (cr >> 3); // write-side 8-half block index

    // ---- stage x[b0..b0+3][t] -> x_lds[t][r]; zero h bufs ----
    for (int idx = tid; idx < 4 * T_STEPS; idx += 512) {
        const int r = idx >> 9, t = idx & (T_STEPS - 1);
        x_lds[t][r] = x[(long)(b0 + r) * T_STEPS + t];
    }
    for (int idx = tid; idx < 2 * 1024; idx += 512) {
        bufA[idx] = (_Float16)0.f;      // junk M-rows stay 0 forever
        bufB[idx] = (_Float16)0.f;
    }

    // ---- per-lane weight fragments (registers), role-specialized ----
    half8 wf[4][4];                 // L0 uses [g][0..1]; L1 uses [g][0..3]
    float bias[4], wi0[4];
    #pragma unroll
    for (int g = 0; g < 4; ++g) {
        const float sc = (g == 2) ? TANH_K : SIG_K;   // gate 2 = g (tanh)
        const int col = g * 64 + ucol;                // PyTorch i,f,g,o
        if (isL0) {
            bias[g] = (b_ih0[col] + b_hh0[col]) * sc;
            wi0[g]  = w_ih0[col] * sc;
            #pragma unroll
            for (int kt = 0; kt < 2; ++kt) {
                const float* src = w_hh0 + col * 64 + kt * 32 + kg * 8;
                #pragma unroll
                for (int i = 0; i < 8; ++i) wf[g][kt][i] = (_Float16)(src[i] * sc);
            }
        } else {
            bias[g] = (b_ih1[col] + b_hh1[col]) * sc;
            #pragma unroll
            for (int kt = 0; kt < 4; ++kt) {
                const int k0 = kt * 32 + kg * 8;   // 0..119 in [h0;h1]
                const float* src = (k0 < 64) ? (w_ih1 + col * 64 + k0)
                                             : (w_hh1 + col * 64 + (k0 - 64));
                #pragma unroll
                for (int i = 0; i < 8; ++i) wf[g][kt][i] = (_Float16)(src[i] * sc);
            }
        }
    }

    const float4_t zero4 = {0.f, 0.f, 0.f, 0.f};
    float cc = 0.f;                     // this lane's single cell state
    float hv = 0.f;

    __syncthreads();   // x_lds + zeroed bufs visible

    for (int k = 0; k <= T_STEPS; ++k) {
        const int sA = (k + 1) & 1;     // slot of h0(k-1)  (h0(-1)=0 in slot 1)

        if (isL0) {
            if (k < T_STEPS) {          // ---- L0: h0(k), cell (batch kg, unit ucol) ----
                const half8 a0 = *(const half8*)&bufA[hoff(sA, cr, kg,     0)];
                const half8 a1 = *(const half8*)&bufA[hoff(sA, cr, 4 + kg, 0)];
                float4_t acc[4];
                #pragma unroll
                for (int g = 0; g < 4; ++g) {
                    acc[g] = __builtin_amdgcn_mfma_f32_16x16x32_f16(a0, wf[g][0], zero4, 0, 0, 0);
                    acc[g] = __builtin_amdgcn_mfma_f32_16x16x32_f16(a1, wf[g][1], acc[g], 0, 0, 0);
                }
                const float xv = x_lds[k][kg];
                const float zi = fmaf(xv, wi0[0], acc[0][0] + bias[0]);
                const float zf = fmaf(xv, wi0[1], acc[1][0] + bias[1]);
                const float zg = fmaf(xv, wi0[2], acc[2][0] + bias[2]);
                const float zo = fmaf(xv, wi0[3], acc[3][0] + bias[3]);
                const float h = lstm_cell(zi, zf, zg, zo, cc);
                bufA[hoff(k & 1, rb, wkb, cr & 7)] = (_Float16)h;
            }
        } else {
            if (k >= 1) {               // ---- L1: h1(k-1), cell (batch kg, unit ucol) ----
                const int sB = k & 1;   // slot of h1(k-2)  (h1(-1)=0 in slot 1)
                const half8 a0  = *(const half8*)&bufA[hoff(sA, cr, kg,     0)];
                const half8 a1  = *(const half8*)&bufA[hoff(sA, cr, 4 + kg, 0)];
                const half8 bh0 = *(const half8*)&bufB[hoff(sB, cr, kg,     0)];
                const half8 bh1 = *(const half8*)&bufB[hoff(sB, cr, 4 + kg, 0)];
                float4_t acc[4];
                #pragma unroll
                for (int g = 0; g < 4; ++g) {
                    acc[g] = __builtin_amdgcn_mfma_f32_16x16x32_f16(a0,  wf[g][0], zero4, 0, 0, 0);
                    acc[g] = __builtin_amdgcn_mfma_f32_16x16x32_f16(a1,  wf[g][1], acc[g], 0, 0, 0);
                    acc[g] = __builtin_amdgcn_mfma_f32_16x16x32_f16(bh0, wf[g][2], acc[g], 0, 0, 0);
                    acc[g] = __builtin_amdgcn_mfma_f32_16x16x32_f16(bh1, wf[g][3], acc[g], 0, 0, 0);
                }
                const float zi = acc[0][0] + bias[0];
                const float zf = acc[1][0] + bias[1];
                const float zg = acc[2][0] + bias[2];
                const float zo = acc[3][0] + bias[3];
                hv = lstm_cell(zi, zf, zg, zo, cc);
                bufB[hoff((k + 1) & 1, rb, wkb, cr & 7)] = (_Float16)hv;
            }
        }

        __syncthreads();    // writes of iter k visible at iter k+1
    }

    // ---- FC head: h_last = h1(511), held by L1 waves (1 cell each) ----
    if (!isL0) {
        hfin[kg][ucol] = hv;
    }
    __syncthreads();

    if (tid < 12) {
        const int row = tid / 3, cls = tid - row * 3;
        float s = b_fc[cls];
        const float* wr = w_fc + cls * 64;
        #pragma unroll 8
        for (int uu = 0; uu < 64; ++uu) s += hfin[row][uu] * wr[uu];
        out[(long)(b0 + row) * 3 + cls] = s;
    }
}

extern "C" void kernel_launch(void* const* d_in, const int* in_sizes, int n_in,
                              void* d_out, int out_size, void* d_ws, size_t ws_size,
                              hipStream_t stream) {
    const float* xx     = (const float*)d_in[0];
    const float* w_ih0  = (const float*)d_in[1];
    const float* w_hh0  = (const float*)d_in[2];
    const float* b_ih0  = (const float*)d_in[3];
    const float* b_hh0  = (const float*)d_in[4];
    const float* w_ih1  = (const float*)d_in[5];
    const float* w_hh1  = (const float*)d_in[6];
    const float* b_ih1  = (const float*)d_in[7];
    const float* b_hh1  = (const float*)d_in[8];
    const float* w_fc   = (const float*)d_in[9];
    const float* b_fc   = (const float*)d_in[10];
    float* out = (float*)d_out;

    lstm2_mfma<<<dim3(512), dim3(512), 0, stream>>>(
        xx, w_ih0, w_hh0, b_ih0, b_hh0,
        w_ih1, w_hh1, b_ih1, b_hh1, w_fc, b_fc, out);
}

// Round 13
// 229.670 us; speedup vs baseline: 1.2014x; 1.2014x over previous
//
#include <hip/hip_runtime.h>

// LSTMClassifier round 12: round-10 geometry + k-loop unroll-2 with fully
// hoisted LDS addressing (per-iter addr/slot math was ~100-150 cyc/wave).
//   grid = 256 blocks x 512 threads (8 waves). Block = 8 batch rows.
//   Waves 0-3: L0 tile u: h0(k) = f(h0(k-1))               [k <= 511]
//   Waves 4-7: L1 tile u: h1(k-1) = f(h0(k-1), h1(k-2))    [k >= 1]
//   Batch row b -> M-row 4*(b>>1)+(b&1): each lane's acc[g][0..1] are its 2
//   real cells; junk M-rows stay exactly 0 (zeroed once, never written).
//   Phases: PH0 (even k): L0 reads A-slot1/writes A-slot0, L1 reads B-slot0/
//   writes B-slot1. PH1 (odd k): all flipped. Peel k=0, 255 pairs, tail 511/512.
//   XOR-rotated h layout (conflict-free b64 gathers, <=2-way b16 writes);
//   merged-rcp activations (5 exp2 + 2 rcp); -log2e pre-scaled weights/biases.

typedef _Float16 half8    __attribute__((ext_vector_type(8)));
typedef float    float4_t __attribute__((ext_vector_type(4)));
typedef float    float2_t __attribute__((ext_vector_type(2)));

#define T_STEPS 512
#define SIG_K  (-1.442695040888963f)    // -log2(e)
#define TANH_K (-2.885390081777927f)    // -2*log2(e)

__device__ __forceinline__ int hoff(int slot, int row, int kb, int lo) {
    return slot * 1024 + row * 64 + (((kb + row) & 7) << 3) + lo;
}

// inputs pre-scaled: zi,zf,zo by -log2e; zg by -2log2e. c updated in place.
// returns h = sigmoid(o)*tanh(c'). 5 exp2 + 2 rcp.
__device__ __forceinline__ float lstm_cell(float zi, float zf, float zg, float zo,
                                           float& c) {
    const float ei = __builtin_amdgcn_exp2f(zi);
    const float ef = __builtin_amdgcn_exp2f(zf);
    const float v  = __builtin_amdgcn_exp2f(zg);
    const float eo = __builtin_amdgcn_exp2f(zo);
    const float pi = 1.f + ei, pf = 1.f + ef, pv = 1.f + v, po = 1.f + eo;
    const float A   = pi * pv;
    const float num = fmaf(c, A, (1.f - v) * pf);
    const float cn  = num * __builtin_amdgcn_rcpf(pf * A);
    c = cn;
    const float u = __builtin_amdgcn_exp2f(cn * TANH_K);
    return (1.f - u) * __builtin_amdgcn_rcpf(po * (1.f + u));
}

extern "C" __global__ __launch_bounds__(512, 1)
void lstm2_mfma(const float* __restrict__ x,
                const float* __restrict__ w_ih0, const float* __restrict__ w_hh0,
                const float* __restrict__ b_ih0, const float* __restrict__ b_hh0,
                const float* __restrict__ w_ih1, const float* __restrict__ w_hh1,
                const float* __restrict__ b_ih1, const float* __restrict__ b_hh1,
                const float* __restrict__ w_fc,  const float* __restrict__ b_fc,
                float* __restrict__ out)
{
    __shared__ float    x_lds[T_STEPS][8];     // 16 KB
    __shared__ _Float16 bufA[2 * 1024];        // h0, 2 slots, 4 KB
    __shared__ _Float16 bufB[2 * 1024];        // h1, 2 slots, 4 KB
    __shared__ float    hfin[8][68];

    const int tid  = threadIdx.x;
    const int wv   = tid >> 6;          // wave 0..7
    const int lane = tid & 63;
    const int cr   = lane & 15;         // A-row (M-row) / C-col (unit)
    const int kg   = lane >> 4;         // k-group 0..3
    const int rb   = kg * 4;            // C-frag row base (cells at rb, rb+1)
    const int b0   = blockIdx.x * 8;    // this block's 8 batch rows
    const bool isL0 = (wv < 4);
    const int u    = wv & 3;            // unit tile 0..3
    const int ucol = u * 16 + cr;       // this lane's unit 0..63
    const int wkb  = 2 * u + (cr >> 3); // write-side 8-half block index

    // ---- stage x[b0..b0+7][t] -> x_lds[t][r]; zero h bufs ----
    for (int idx = tid; idx < 8 * T_STEPS; idx += 512) {
        const int r = idx >> 9, t = idx & (T_STEPS - 1);
        x_lds[t][r] = x[(long)(b0 + r) * T_STEPS + t];
    }
    for (int idx = tid; idx < 2 * 1024; idx += 512) {
        bufA[idx] = (_Float16)0.f;      // junk M-rows stay 0 forever
        bufB[idx] = (_Float16)0.f;
    }

    // ---- per-lane weight fragments (registers), role-specialized ----
    half8 wf[4][4];                 // L0 uses [g][0..1]; L1 uses [g][0..3]
    float bias[4], wi0[4];
    #pragma unroll
    for (int g = 0; g < 4; ++g) {
        const float sc = (g == 2) ? TANH_K : SIG_K;   // gate 2 = g (tanh)
        const int col = g * 64 + ucol;                // PyTorch i,f,g,o
        if (isL0) {
            bias[g] = (b_ih0[col] + b_hh0[col]) * sc;
            wi0[g]  = w_ih0[col] * sc;
            #pragma unroll
            for (int kt = 0; kt < 2; ++kt) {
                const float* src = w_hh0 + col * 64 + kt * 32 + kg * 8;
                #pragma unroll
                for (int i = 0; i < 8; ++i) wf[g][kt][i] = (_Float16)(src[i] * sc);
            }
        } else {
            bias[g] = (b_ih1[col] + b_hh1[col]) * sc;
            #pragma unroll
            for (int kt = 0; kt < 4; ++kt) {
                const int k0 = kt * 32 + kg * 8;   // 0..119 in [h0;h1]
                const float* src = (k0 < 64) ? (w_ih1 + col * 64 + k0)
                                             : (w_hh1 + col * 64 + (k0 - 64));
                #pragma unroll
                for (int i = 0; i < 8; ++i) wf[g][kt][i] = (_Float16)(src[i] * sc);
            }
        }
    }

    // ---- hoisted LDS offsets (in halfs), both slots ----
    const int rd0s0 = hoff(0, cr, kg,     0), rd0s1 = hoff(1, cr, kg,     0);
    const int rd1s0 = hoff(0, cr, 4 + kg, 0), rd1s1 = hoff(1, cr, 4 + kg, 0);
    const int w0s0  = hoff(0, rb,     wkb, cr & 7);
    const int w1s0  = hoff(0, rb + 1, wkb, cr & 7);
    const int w0s1  = hoff(1, rb,     wkb, cr & 7);
    const int w1s1  = hoff(1, rb + 1, wkb, cr & 7);

    const float4_t zero4 = {0.f, 0.f, 0.f, 0.f};
    float cc0 = 0.f, cc1 = 0.f;         // this lane's 2 cell states
    float hv0 = 0.f, hv1 = 0.f;

    auto l0_step = [&](int kk, int rd0, int rd1, int wo0, int wo1)
        __attribute__((always_inline)) {
        const half8 a0 = *(const half8*)&bufA[rd0];
        const half8 a1 = *(const half8*)&bufA[rd1];
        float4_t acc[4];
        #pragma unroll
        for (int g = 0; g < 4; ++g) {
            acc[g] = __builtin_amdgcn_mfma_f32_16x16x32_f16(a0, wf[g][0], zero4, 0, 0, 0);
            acc[g] = __builtin_amdgcn_mfma_f32_16x16x32_f16(a1, wf[g][1], acc[g], 0, 0, 0);
        }
        const float2_t xq = *(const float2_t*)&x_lds[kk][2 * kg];
        {
            const float zi = fmaf(xq[0], wi0[0], acc[0][0] + bias[0]);
            const float zf = fmaf(xq[0], wi0[1], acc[1][0] + bias[1]);
            const float zg = fmaf(xq[0], wi0[2], acc[2][0] + bias[2]);
            const float zo = fmaf(xq[0], wi0[3], acc[3][0] + bias[3]);
            bufA[wo0] = (_Float16)lstm_cell(zi, zf, zg, zo, cc0);
        }
        {
            const float zi = fmaf(xq[1], wi0[0], acc[0][1] + bias[0]);
            const float zf = fmaf(xq[1], wi0[1], acc[1][1] + bias[1]);
            const float zg = fmaf(xq[1], wi0[2], acc[2][1] + bias[2]);
            const float zo = fmaf(xq[1], wi0[3], acc[3][1] + bias[3]);
            bufA[wo1] = (_Float16)lstm_cell(zi, zf, zg, zo, cc1);
        }
    };
    auto l1_step = [&](int rd0, int rd1, int rB0, int rB1, int wo0, int wo1)
        __attribute__((always_inline)) {
        const half8 a0  = *(const half8*)&bufA[rd0];
        const half8 a1  = *(const half8*)&bufA[rd1];
        const half8 bh0 = *(const half8*)&bufB[rB0];
        const half8 bh1 = *(const half8*)&bufB[rB1];
        float4_t acc[4];
        #pragma unroll
        for (int g = 0; g < 4; ++g) {
            acc[g] = __builtin_amdgcn_mfma_f32_16x16x32_f16(a0,  wf[g][0], zero4, 0, 0, 0);
            acc[g] = __builtin_amdgcn_mfma_f32_16x16x32_f16(a1,  wf[g][1], acc[g], 0, 0, 0);
            acc[g] = __builtin_amdgcn_mfma_f32_16x16x32_f16(bh0, wf[g][2], acc[g], 0, 0, 0);
            acc[g] = __builtin_amdgcn_mfma_f32_16x16x32_f16(bh1, wf[g][3], acc[g], 0, 0, 0);
        }
        {
            const float zi = acc[0][0] + bias[0];
            const float zf = acc[1][0] + bias[1];
            const float zg = acc[2][0] + bias[2];
            const float zo = acc[3][0] + bias[3];
            hv0 = lstm_cell(zi, zf, zg, zo, cc0);
            bufB[wo0] = (_Float16)hv0;
        }
        {
            const float zi = acc[0][1] + bias[0];
            const float zf = acc[1][1] + bias[1];
            const float zg = acc[2][1] + bias[2];
            const float zo = acc[3][1] + bias[3];
            hv1 = lstm_cell(zi, zf, zg, zo, cc1);
            bufB[wo1] = (_Float16)hv1;
        }
    };

    __syncthreads();   // x_lds + zeroed bufs visible

    // ---- k = 0 (PH0): L0 only (reads A-s1 = h0(-1)=0, writes A-s0) ----
    if (isL0) l0_step(0, rd0s1, rd1s1, w0s0, w1s0);
    __syncthreads();

    // ---- 255 pairs: (odd k, even k+1), k = 1..509 ----
    for (int k = 1; k <= 509; k += 2) {
        // PH1 (odd k): L0 reads A-s0 writes A-s1; L1 reads A-s0 + B-s1, writes B-s0
        if (isL0) l0_step(k, rd0s0, rd1s0, w0s1, w1s1);
        else      l1_step(rd0s0, rd1s0, rd0s1, rd1s1, w0s0, w1s0);
        __syncthreads();
        // PH0 (even k+1): L0 reads A-s1 writes A-s0; L1 reads A-s1 + B-s0, writes B-s1
        if (isL0) l0_step(k + 1, rd0s1, rd1s1, w0s0, w1s0);
        else      l1_step(rd0s1, rd1s1, rd0s0, rd1s0, w0s1, w1s1);
        __syncthreads();
    }

    // ---- k = 511 (PH1): L0 last step + L1 ----
    if (isL0) l0_step(511, rd0s0, rd1s0, w0s1, w1s1);
    else      l1_step(rd0s0, rd1s0, rd0s1, rd1s1, w0s0, w1s0);
    __syncthreads();
    // ---- k = 512 (PH0): L1 only (h1(511)) ----
    if (!isL0) l1_step(rd0s1, rd1s1, rd0s0, rd1s0, w0s1, w1s1);
    __syncthreads();

    // ---- FC head: h_last = h1(511), held by L1 waves (2 batch rows each) ----
    if (!isL0) {
        hfin[2 * kg + 0][ucol] = hv0;
        hfin[2 * kg + 1][ucol] = hv1;
    }
    __syncthreads();

    if (tid < 24) {
        const int row = tid / 3, cls = tid - row * 3;
        float s = b_fc[cls];
        const float* wr = w_fc + cls * 64;
        #pragma unroll 8
        for (int uu = 0; uu < 64; ++uu) s += hfin[row][uu] * wr[uu];
        out[(long)(b0 + row) * 3 + cls] = s;
    }
}

extern "C" void kernel_launch(void* const* d_in, const int* in_sizes, int n_in,
                              void* d_out, int out_size, void* d_ws, size_t ws_size,
                              hipStream_t stream) {
    const float* xx     = (const float*)d_in[0];
    const float* w_ih0  = (const float*)d_in[1];
    const float* w_hh0  = (const float*)d_in[2];
    const float* b_ih0  = (const float*)d_in[3];
    const float* b_hh0  = (const float*)d_in[4];
    const float* w_ih1  = (const float*)d_in[5];
    const float* w_hh1  = (const float*)d_in[6];
    const float* b_ih1  = (const float*)d_in[7];
    const float* b_hh1  = (const float*)d_in[8];
    const float* w_fc   = (const float*)d_in[9];
    const float* b_fc   = (const float*)d_in[10];
    float* out = (float*)d_out;

    lstm2_mfma<<<dim3(256), dim3(512), 0, stream>>>(
        xx, w_ih0, w_hh0, b_ih0, b_hh0,
        w_ih1, w_hh1, b_ih1, b_hh1, w_fc, b_fc, out);
}

// Round 14
// 229.046 us; speedup vs baseline: 1.2046x; 1.0027x over previous
//
#include <hip/hip_runtime.h>

// LSTMClassifier round 13: round-12 + skew-2 L1 with register-prefetched h0.
//   grid = 256 blocks x 512 threads (8 waves). Block = 8 batch rows.
//   Waves 0-3: L0 tile u: h0(k)   = f(h0(k-1))             [iters k = 0..511]
//   Waves 4-7: L1 tile u: h1(k-2) = f(h0(k-2), h1(k-3))    [iters k = 2..513]
//   L1's h0(k-2) is consumed from REGISTERS prefetched at iter k-1 (published
//   two barriers back -> prefetch races nothing). L1's MFMA order: 8 reg-fed
//   h0-part MFMAs first (fire at barrier-exit, overlap L0's read latency),
//   then h1-part (bufB read latency hides under the burst).
//   Slots stay parity-based: bufA write k&1 / read (k-1)&1 (prefetch reads the
//   read-slot, never the write-slot). bufB write k&1, read (k-1)&1.
//   Batch row b -> M-row 4*(b>>1)+(b&1): acc[g][0..1] real, junk rows stay 0.
//   XOR-rotated h layout; merged-rcp activations (5 exp2 + 2 rcp);
//   -log2e pre-scaled weights/biases. One s_barrier per iter.

typedef _Float16 half8    __attribute__((ext_vector_type(8)));
typedef float    float4_t __attribute__((ext_vector_type(4)));
typedef float    float2_t __attribute__((ext_vector_type(2)));

#define T_STEPS 512
#define SIG_K  (-1.442695040888963f)    // -log2(e)
#define TANH_K (-2.885390081777927f)    // -2*log2(e)

__device__ __forceinline__ int hoff(int slot, int row, int kb, int lo) {
    return slot * 1024 + row * 64 + (((kb + row) & 7) << 3) + lo;
}

// inputs pre-scaled: zi,zf,zo by -log2e; zg by -2log2e. c updated in place.
// returns h = sigmoid(o)*tanh(c'). 5 exp2 + 2 rcp.
__device__ __forceinline__ float lstm_cell(float zi, float zf, float zg, float zo,
                                           float& c) {
    const float ei = __builtin_amdgcn_exp2f(zi);
    const float ef = __builtin_amdgcn_exp2f(zf);
    const float v  = __builtin_amdgcn_exp2f(zg);
    const float eo = __builtin_amdgcn_exp2f(zo);
    const float pi = 1.f + ei, pf = 1.f + ef, pv = 1.f + v, po = 1.f + eo;
    const float A   = pi * pv;
    const float num = fmaf(c, A, (1.f - v) * pf);
    const float cn  = num * __builtin_amdgcn_rcpf(pf * A);
    c = cn;
    const float u = __builtin_amdgcn_exp2f(cn * TANH_K);
    return (1.f - u) * __builtin_amdgcn_rcpf(po * (1.f + u));
}

extern "C" __global__ __launch_bounds__(512, 1)
void lstm2_mfma(const float* __restrict__ x,
                const float* __restrict__ w_ih0, const float* __restrict__ w_hh0,
                const float* __restrict__ b_ih0, const float* __restrict__ b_hh0,
                const float* __restrict__ w_ih1, const float* __restrict__ w_hh1,
                const float* __restrict__ b_ih1, const float* __restrict__ b_hh1,
                const float* __restrict__ w_fc,  const float* __restrict__ b_fc,
                float* __restrict__ out)
{
    __shared__ float    x_lds[T_STEPS][8];     // 16 KB
    __shared__ _Float16 bufA[2 * 1024];        // h0, 2 slots, 4 KB
    __shared__ _Float16 bufB[2 * 1024];        // h1, 2 slots, 4 KB
    __shared__ float    hfin[8][68];

    const int tid  = threadIdx.x;
    const int wv   = tid >> 6;          // wave 0..7
    const int lane = tid & 63;
    const int cr   = lane & 15;         // A-row (M-row) / C-col (unit)
    const int kg   = lane >> 4;         // k-group 0..3
    const int rb   = kg * 4;            // C-frag row base (cells at rb, rb+1)
    const int b0   = blockIdx.x * 8;    // this block's 8 batch rows
    const bool isL0 = (wv < 4);
    const int u    = wv & 3;            // unit tile 0..3
    const int ucol = u * 16 + cr;       // this lane's unit 0..63
    const int wkb  = 2 * u + (cr >> 3); // write-side 8-half block index

    // ---- stage x[b0..b0+7][t] -> x_lds[t][r]; zero h bufs ----
    for (int idx = tid; idx < 8 * T_STEPS; idx += 512) {
        const int r = idx >> 9, t = idx & (T_STEPS - 1);
        x_lds[t][r] = x[(long)(b0 + r) * T_STEPS + t];
    }
    for (int idx = tid; idx < 2 * 1024; idx += 512) {
        bufA[idx] = (_Float16)0.f;      // junk M-rows stay 0 forever
        bufB[idx] = (_Float16)0.f;
    }

    // ---- per-lane weight fragments (registers), role-specialized ----
    half8 wf[4][4];                 // L0 uses [g][0..1]; L1 uses [g][0..3]
    float bias[4], wi0[4];
    #pragma unroll
    for (int g = 0; g < 4; ++g) {
        const float sc = (g == 2) ? TANH_K : SIG_K;   // gate 2 = g (tanh)
        const int col = g * 64 + ucol;                // PyTorch i,f,g,o
        if (isL0) {
            bias[g] = (b_ih0[col] + b_hh0[col]) * sc;
            wi0[g]  = w_ih0[col] * sc;
            #pragma unroll
            for (int kt = 0; kt < 2; ++kt) {
                const float* src = w_hh0 + col * 64 + kt * 32 + kg * 8;
                #pragma unroll
                for (int i = 0; i < 8; ++i) wf[g][kt][i] = (_Float16)(src[i] * sc);
            }
        } else {
            bias[g] = (b_ih1[col] + b_hh1[col]) * sc;
            #pragma unroll
            for (int kt = 0; kt < 4; ++kt) {
                const int k0 = kt * 32 + kg * 8;   // 0..119 in [h0;h1]
                const float* src = (k0 < 64) ? (w_ih1 + col * 64 + k0)
                                             : (w_hh1 + col * 64 + (k0 - 64));
                #pragma unroll
                for (int i = 0; i < 8; ++i) wf[g][kt][i] = (_Float16)(src[i] * sc);
            }
        }
    }

    // ---- hoisted LDS offsets (in halfs), both slots ----
    const int rd0s0 = hoff(0, cr, kg,     0), rd0s1 = hoff(1, cr, kg,     0);
    const int rd1s0 = hoff(0, cr, 4 + kg, 0), rd1s1 = hoff(1, cr, 4 + kg, 0);
    const int w0s0  = hoff(0, rb,     wkb, cr & 7);
    const int w1s0  = hoff(0, rb + 1, wkb, cr & 7);
    const int w0s1  = hoff(1, rb,     wkb, cr & 7);
    const int w1s1  = hoff(1, rb + 1, wkb, cr & 7);

    const float4_t zero4 = {0.f, 0.f, 0.f, 0.f};
    float cc0 = 0.f, cc1 = 0.f;         // this lane's 2 cell states
    float hv0 = 0.f, hv1 = 0.f;
    half8 pa0 = {}, pa1 = {};           // L1: prefetched h0 fragments

    auto l0_step = [&](int kk, int rd0, int rd1, int wo0, int wo1)
        __attribute__((always_inline)) {
        const half8 a0 = *(const half8*)&bufA[rd0];
        const half8 a1 = *(const half8*)&bufA[rd1];
        float4_t acc[4];
        #pragma unroll
        for (int g = 0; g < 4; ++g) {
            acc[g] = __builtin_amdgcn_mfma_f32_16x16x32_f16(a0, wf[g][0], zero4, 0, 0, 0);
            acc[g] = __builtin_amdgcn_mfma_f32_16x16x32_f16(a1, wf[g][1], acc[g], 0, 0, 0);
        }
        const float2_t xq = *(const float2_t*)&x_lds[kk][2 * kg];
        {
            const float zi = fmaf(xq[0], wi0[0], acc[0][0] + bias[0]);
            const float zf = fmaf(xq[0], wi0[1], acc[1][0] + bias[1]);
            const float zg = fmaf(xq[0], wi0[2], acc[2][0] + bias[2]);
            const float zo = fmaf(xq[0], wi0[3], acc[3][0] + bias[3]);
            bufA[wo0] = (_Float16)lstm_cell(zi, zf, zg, zo, cc0);
        }
        {
            const float zi = fmaf(xq[1], wi0[0], acc[0][1] + bias[0]);
            const float zf = fmaf(xq[1], wi0[1], acc[1][1] + bias[1]);
            const float zg = fmaf(xq[1], wi0[2], acc[2][1] + bias[2]);
            const float zo = fmaf(xq[1], wi0[3], acc[3][1] + bias[3]);
            bufA[wo1] = (_Float16)lstm_cell(zi, zf, zg, zo, cc1);
        }
    };

    // L1 step: consume prefetched h0 (pa0/pa1); prefetch next h0 from prd*;
    // bufB read latency hides under the 8 reg-fed MFMAs.
    auto l1_step = [&](int rB0, int rB1, int wo0, int wo1, int prd0, int prd1)
        __attribute__((always_inline)) {
        const half8 n0  = *(const half8*)&bufA[prd0];   // prefetch next h0
        const half8 n1  = *(const half8*)&bufA[prd1];
        const half8 bh0 = *(const half8*)&bufB[rB0];
        const half8 bh1 = *(const half8*)&bufB[rB1];
        float4_t acc[4];
        #pragma unroll
        for (int g = 0; g < 4; ++g) {       // h0 part: registers, fires at t=0
            acc[g] = __builtin_amdgcn_mfma_f32_16x16x32_f16(pa0, wf[g][0], zero4, 0, 0, 0);
            acc[g] = __builtin_amdgcn_mfma_f32_16x16x32_f16(pa1, wf[g][1], acc[g], 0, 0, 0);
        }
        #pragma unroll
        for (int g = 0; g < 4; ++g) {       // h1 part: read latency hidden above
            acc[g] = __builtin_amdgcn_mfma_f32_16x16x32_f16(bh0, wf[g][2], acc[g], 0, 0, 0);
            acc[g] = __builtin_amdgcn_mfma_f32_16x16x32_f16(bh1, wf[g][3], acc[g], 0, 0, 0);
        }
        {
            const float zi = acc[0][0] + bias[0];
            const float zf = acc[1][0] + bias[1];
            const float zg = acc[2][0] + bias[2];
            const float zo = acc[3][0] + bias[3];
            hv0 = lstm_cell(zi, zf, zg, zo, cc0);
            bufB[wo0] = (_Float16)hv0;
        }
        {
            const float zi = acc[0][1] + bias[0];
            const float zf = acc[1][1] + bias[1];
            const float zg = acc[2][1] + bias[2];
            const float zo = acc[3][1] + bias[3];
            hv1 = lstm_cell(zi, zf, zg, zo, cc1);
            bufB[wo1] = (_Float16)hv1;
        }
        pa0 = n0; pa1 = n1;
    };

    __syncthreads();   // x_lds + zeroed bufs visible

    // ---- iter 0: L0 only (reads slot1 = h0(-1)=0, writes slot0) ----
    if (isL0) l0_step(0, rd0s1, rd1s1, w0s0, w1s0);
    __syncthreads();
    // ---- iter 1: L0; L1 prefetches h0(0) from slot0 ----
    if (isL0) l0_step(1, rd0s0, rd1s0, w0s1, w1s1);
    else { pa0 = *(const half8*)&bufA[rd0s0]; pa1 = *(const half8*)&bufA[rd1s0]; }
    __syncthreads();

    // ---- 255 pairs: k = 2,4,...,510 (covers iters 2..511) ----
    for (int k = 2; k <= 510; k += 2) {
        // even k: L0 reads s1 writes s0; L1 computes h1(k-2) (bufB: read s1,
        // write s0), prefetches h0(k-1) from s1
        if (isL0) l0_step(k, rd0s1, rd1s1, w0s0, w1s0);
        else      l1_step(rd0s1, rd1s1, w0s0, w1s0, rd0s1, rd1s1);
        __syncthreads();
        // odd k+1: all slots flipped
        if (isL0) l0_step(k + 1, rd0s0, rd1s0, w0s1, w1s1);
        else      l1_step(rd0s0, rd1s0, w0s1, w1s1, rd0s0, rd1s0);
        __syncthreads();
    }

    // ---- iter 512 (even): L1 computes h1(510); prefetch h0(511) from s1 ----
    if (!isL0) l1_step(rd0s1, rd1s1, w0s0, w1s0, rd0s1, rd1s1);
    __syncthreads();
    // ---- iter 513 (odd): L1 computes h1(511); dummy prefetch (harmless) ----
    if (!isL0) l1_step(rd0s0, rd1s0, w0s1, w1s1, rd0s0, rd1s0);
    __syncthreads();

    // ---- FC head: h_last = h1(511), held by L1 waves (2 batch rows each) ----
    if (!isL0) {
        hfin[2 * kg + 0][ucol] = hv0;
        hfin[2 * kg + 1][ucol] = hv1;
    }
    __syncthreads();

    if (tid < 24) {
        const int row = tid / 3, cls = tid - row * 3;
        float s = b_fc[cls];
        const float* wr = w_fc + cls * 64;
        #pragma unroll 8
        for (int uu = 0; uu < 64; ++uu) s += hfin[row][uu] * wr[uu];
        out[(long)(b0 + row) * 3 + cls] = s;
    }
}

extern "C" void kernel_launch(void* const* d_in, const int* in_sizes, int n_in,
                              void* d_out, int out_size, void* d_ws, size_t ws_size,
                              hipStream_t stream) {
    const float* xx     = (const float*)d_in[0];
    const float* w_ih0  = (const float*)d_in[1];
    const float* w_hh0  = (const float*)d_in[2];
    const float* b_ih0  = (const float*)d_in[3];
    const float* b_hh0  = (const float*)d_in[4];
    const float* w_ih1  = (const float*)d_in[5];
    const float* w_hh1  = (const float*)d_in[6];
    const float* b_ih1  = (const float*)d_in[7];
    const float* b_hh1  = (const float*)d_in[8];
    const float* w_fc   = (const float*)d_in[9];
    const float* b_fc   = (const float*)d_in[10];
    float* out = (float*)d_out;

    lstm2_mfma<<<dim3(256), dim3(512), 0, stream>>>(
        xx, w_ih0, w_hh0, b_ih0, b_hh0,
        w_ih1, w_hh1, b_ih1, b_hh1, w_fc, b_fc, out);
}

// Round 15
// 219.161 us; speedup vs baseline: 1.2590x; 1.0451x over previous
//
#include <hip/hip_runtime.h>

// LSTMClassifier round 14: round-12 structure + issue diet.
//   (1) gate bias pre-loaded into MFMA C operand (hoisted float4 broadcast)
//   (2) epilogue processes the wave's 2 cells as packed float2 (v_pk_*_f32)
//   (3) L0 x-fold = one pk_fma per gate
//   grid = 256 blocks x 512 threads (8 waves). Block = 8 batch rows.
//   Waves 0-3: L0 tile u: h0(k) = f(h0(k-1))               [k <= 511]
//   Waves 4-7: L1 tile u: h1(k-1) = f(h0(k-1), h1(k-2))    [k >= 1]
//   Batch row b -> M-row 4*(b>>1)+(b&1): acc[g][0..1] real; junk rows stay 0.
//   Unroll-2 k-loop, fully hoisted LDS offsets, one s_barrier per iter.
//   XOR-rotated h layout; merged-rcp activations (5 exp2 + 2 rcp per cell);
//   -log2e pre-scaled weights/biases.

typedef _Float16 half8    __attribute__((ext_vector_type(8)));
typedef float    float4_t __attribute__((ext_vector_type(4)));
typedef float    float2v  __attribute__((ext_vector_type(2)));

#define T_STEPS 512
#define SIG_K  (-1.442695040888963f)    // -log2(e)
#define TANH_K (-2.885390081777927f)    // -2*log2(e)

__device__ __forceinline__ int hoff(int slot, int row, int kb, int lo) {
    return slot * 1024 + row * 64 + (((kb + row) & 7) << 3) + lo;
}

// Packed 2-cell LSTM epilogue. Inputs pre-scaled (zi,zf,zo by -log2e, zg by
// -2log2e) and already bias-folded. c updated in place. 10 exp2 + 4 rcp for
// the pair; all other math packed float2 (v_pk_*_f32).
__device__ __forceinline__ float2v lstm_cell2(float2v zi, float2v zf,
                                              float2v zg, float2v zo,
                                              float2v& c) {
    float2v ei, ef, vv, eo;
    ei[0] = __builtin_amdgcn_exp2f(zi[0]); ei[1] = __builtin_amdgcn_exp2f(zi[1]);
    ef[0] = __builtin_amdgcn_exp2f(zf[0]); ef[1] = __builtin_amdgcn_exp2f(zf[1]);
    vv[0] = __builtin_amdgcn_exp2f(zg[0]); vv[1] = __builtin_amdgcn_exp2f(zg[1]);
    eo[0] = __builtin_amdgcn_exp2f(zo[0]); eo[1] = __builtin_amdgcn_exp2f(zo[1]);
    const float2v one = {1.f, 1.f};
    const float2v pi = one + ei, pf = one + ef, pv = one + vv, po = one + eo;
    const float2v A   = pi * pv;
    const float2v num = c * A + (one - vv) * pf;
    const float2v d   = pf * A;
    float2v rd;
    rd[0] = __builtin_amdgcn_rcpf(d[0]); rd[1] = __builtin_amdgcn_rcpf(d[1]);
    const float2v cn = num * rd;
    c = cn;
    const float2v ct = cn * TANH_K;
    float2v u;
    u[0] = __builtin_amdgcn_exp2f(ct[0]); u[1] = __builtin_amdgcn_exp2f(ct[1]);
    const float2v den = po * (one + u);
    float2v rn;
    rn[0] = __builtin_amdgcn_rcpf(den[0]); rn[1] = __builtin_amdgcn_rcpf(den[1]);
    return (one - u) * rn;
}

extern "C" __global__ __launch_bounds__(512, 1)
void lstm2_mfma(const float* __restrict__ x,
                const float* __restrict__ w_ih0, const float* __restrict__ w_hh0,
                const float* __restrict__ b_ih0, const float* __restrict__ b_hh0,
                const float* __restrict__ w_ih1, const float* __restrict__ w_hh1,
                const float* __restrict__ b_ih1, const float* __restrict__ b_hh1,
                const float* __restrict__ w_fc,  const float* __restrict__ b_fc,
                float* __restrict__ out)
{
    __shared__ float    x_lds[T_STEPS][8];     // 16 KB
    __shared__ _Float16 bufA[2 * 1024];        // h0, 2 slots, 4 KB
    __shared__ _Float16 bufB[2 * 1024];        // h1, 2 slots, 4 KB
    __shared__ float    hfin[8][68];

    const int tid  = threadIdx.x;
    const int wv   = tid >> 6;          // wave 0..7
    const int lane = tid & 63;
    const int cr   = lane & 15;         // A-row (M-row) / C-col (unit)
    const int kg   = lane >> 4;         // k-group 0..3
    const int rb   = kg * 4;            // C-frag row base (cells at rb, rb+1)
    const int b0   = blockIdx.x * 8;    // this block's 8 batch rows
    const bool isL0 = (wv < 4);
    const int u    = wv & 3;            // unit tile 0..3
    const int ucol = u * 16 + cr;       // this lane's unit 0..63
    const int wkb  = 2 * u + (cr >> 3); // write-side 8-half block index

    // ---- stage x[b0..b0+7][t] -> x_lds[t][r]; zero h bufs ----
    for (int idx = tid; idx < 8 * T_STEPS; idx += 512) {
        const int r = idx >> 9, t = idx & (T_STEPS - 1);
        x_lds[t][r] = x[(long)(b0 + r) * T_STEPS + t];
    }
    for (int idx = tid; idx < 2 * 1024; idx += 512) {
        bufA[idx] = (_Float16)0.f;      // junk M-rows stay 0 forever
        bufB[idx] = (_Float16)0.f;
    }

    // ---- per-lane weight fragments (registers), role-specialized ----
    half8 wf[4][4];                 // L0 uses [g][0..1]; L1 uses [g][0..3]
    float4_t bias4[4];              // gate bias, broadcast (MFMA C-init)
    float2v  wi0b[4];               // L0: x-weight, broadcast pair
    #pragma unroll
    for (int g = 0; g < 4; ++g) {
        const float sc = (g == 2) ? TANH_K : SIG_K;   // gate 2 = g (tanh)
        const int col = g * 64 + ucol;                // PyTorch i,f,g,o
        if (isL0) {
            const float b = (b_ih0[col] + b_hh0[col]) * sc;
            bias4[g] = (float4_t){b, b, b, b};
            const float w = w_ih0[col] * sc;
            wi0b[g] = (float2v){w, w};
            #pragma unroll
            for (int kt = 0; kt < 2; ++kt) {
                const float* src = w_hh0 + col * 64 + kt * 32 + kg * 8;
                #pragma unroll
                for (int i = 0; i < 8; ++i) wf[g][kt][i] = (_Float16)(src[i] * sc);
            }
        } else {
            const float b = (b_ih1[col] + b_hh1[col]) * sc;
            bias4[g] = (float4_t){b, b, b, b};
            wi0b[g] = (float2v){0.f, 0.f};
            #pragma unroll
            for (int kt = 0; kt < 4; ++kt) {
                const int k0 = kt * 32 + kg * 8;   // 0..119 in [h0;h1]
                const float* src = (k0 < 64) ? (w_ih1 + col * 64 + k0)
                                             : (w_hh1 + col * 64 + (k0 - 64));
                #pragma unroll
                for (int i = 0; i < 8; ++i) wf[g][kt][i] = (_Float16)(src[i] * sc);
            }
        }
    }

    // ---- hoisted LDS offsets (in halfs), both slots ----
    const int rd0s0 = hoff(0, cr, kg,     0), rd0s1 = hoff(1, cr, kg,     0);
    const int rd1s0 = hoff(0, cr, 4 + kg, 0), rd1s1 = hoff(1, cr, 4 + kg, 0);
    const int w0s0  = hoff(0, rb,     wkb, cr & 7);
    const int w1s0  = hoff(0, rb + 1, wkb, cr & 7);
    const int w0s1  = hoff(1, rb,     wkb, cr & 7);
    const int w1s1  = hoff(1, rb + 1, wkb, cr & 7);

    float2v cc2 = {0.f, 0.f};           // this lane's 2 cell states
    float2v hv2 = {0.f, 0.f};

    auto l0_step = [&](int kk, int rd0, int rd1, int wo0, int wo1)
        __attribute__((always_inline)) {
        const half8 a0 = *(const half8*)&bufA[rd0];
        const half8 a1 = *(const half8*)&bufA[rd1];
        float4_t acc[4];
        #pragma unroll
        for (int g = 0; g < 4; ++g) {
            acc[g] = __builtin_amdgcn_mfma_f32_16x16x32_f16(a0, wf[g][0], bias4[g], 0, 0, 0);
            acc[g] = __builtin_amdgcn_mfma_f32_16x16x32_f16(a1, wf[g][1], acc[g], 0, 0, 0);
        }
        const float2v xq = *(const float2v*)&x_lds[kk][2 * kg];
        float2v z[4];
        #pragma unroll
        for (int g = 0; g < 4; ++g) {
            const float2v ap = {acc[g][0], acc[g][1]};
            z[g] = xq * wi0b[g] + ap;          // pk_fma
        }
        const float2v h = lstm_cell2(z[0], z[1], z[2], z[3], cc2);
        bufA[wo0] = (_Float16)h[0];
        bufA[wo1] = (_Float16)h[1];
    };
    auto l1_step = [&](int rd0, int rd1, int rB0, int rB1, int wo0, int wo1)
        __attribute__((always_inline)) {
        const half8 a0  = *(const half8*)&bufA[rd0];
        const half8 a1  = *(const half8*)&bufA[rd1];
        const half8 bh0 = *(const half8*)&bufB[rB0];
        const half8 bh1 = *(const half8*)&bufB[rB1];
        float4_t acc[4];
        #pragma unroll
        for (int g = 0; g < 4; ++g) {
            acc[g] = __builtin_amdgcn_mfma_f32_16x16x32_f16(a0,  wf[g][0], bias4[g], 0, 0, 0);
            acc[g] = __builtin_amdgcn_mfma_f32_16x16x32_f16(a1,  wf[g][1], acc[g], 0, 0, 0);
            acc[g] = __builtin_amdgcn_mfma_f32_16x16x32_f16(bh0, wf[g][2], acc[g], 0, 0, 0);
            acc[g] = __builtin_amdgcn_mfma_f32_16x16x32_f16(bh1, wf[g][3], acc[g], 0, 0, 0);
        }
        float2v z[4];
        #pragma unroll
        for (int g = 0; g < 4; ++g)
            z[g] = (float2v){acc[g][0], acc[g][1]};
        hv2 = lstm_cell2(z[0], z[1], z[2], z[3], cc2);
        bufB[wo0] = (_Float16)hv2[0];
        bufB[wo1] = (_Float16)hv2[1];
    };

    __syncthreads();   // x_lds + zeroed bufs visible

    // ---- k = 0 (PH0): L0 only (reads A-s1 = h0(-1)=0, writes A-s0) ----
    if (isL0) l0_step(0, rd0s1, rd1s1, w0s0, w1s0);
    __syncthreads();

    // ---- 255 pairs: (odd k, even k+1), k = 1..509 ----
    for (int k = 1; k <= 509; k += 2) {
        // PH1 (odd k): L0 reads A-s0 writes A-s1; L1 reads A-s0 + B-s1, writes B-s0
        if (isL0) l0_step(k, rd0s0, rd1s0, w0s1, w1s1);
        else      l1_step(rd0s0, rd1s0, rd0s1, rd1s1, w0s0, w1s0);
        __syncthreads();
        // PH0 (even k+1): L0 reads A-s1 writes A-s0; L1 reads A-s1 + B-s0, writes B-s1
        if (isL0) l0_step(k + 1, rd0s1, rd1s1, w0s0, w1s0);
        else      l1_step(rd0s1, rd1s1, rd0s0, rd1s0, w0s1, w1s1);
        __syncthreads();
    }

    // ---- k = 511 (PH1): L0 last step + L1 ----
    if (isL0) l0_step(511, rd0s0, rd1s0, w0s1, w1s1);
    else      l1_step(rd0s0, rd1s0, rd0s1, rd1s1, w0s0, w1s0);
    __syncthreads();
    // ---- k = 512 (PH0): L1 only (h1(511)) ----
    if (!isL0) l1_step(rd0s1, rd1s1, rd0s0, rd1s0, w0s1, w1s1);
    __syncthreads();

    // ---- FC head: h_last = h1(511), held by L1 waves (2 batch rows each) ----
    if (!isL0) {
        hfin[2 * kg + 0][ucol] = hv2[0];
        hfin[2 * kg + 1][ucol] = hv2[1];
    }
    __syncthreads();

    if (tid < 24) {
        const int row = tid / 3, cls = tid - row * 3;
        float s = b_fc[cls];
        const float* wr = w_fc + cls * 64;
        #pragma unroll 8
        for (int uu = 0; uu < 64; ++uu) s += hfin[row][uu] * wr[uu];
        out[(long)(b0 + row) * 3 + cls] = s;
    }
}

extern "C" void kernel_launch(void* const* d_in, const int* in_sizes, int n_in,
                              void* d_out, int out_size, void* d_ws, size_t ws_size,
                              hipStream_t stream) {
    const float* xx     = (const float*)d_in[0];
    const float* w_ih0  = (const float*)d_in[1];
    const float* w_hh0  = (const float*)d_in[2];
    const float* b_ih0  = (const float*)d_in[3];
    const float* b_hh0  = (const float*)d_in[4];
    const float* w_ih1  = (const float*)d_in[5];
    const float* w_hh1  = (const float*)d_in[6];
    const float* b_ih1  = (const float*)d_in[7];
    const float* b_hh1  = (const float*)d_in[8];
    const float* w_fc   = (const float*)d_in[9];
    const float* b_fc   = (const float*)d_in[10];
    float* out = (float*)d_out;

    lstm2_mfma<<<dim3(256), dim3(512), 0, stream>>>(
        xx, w_ih0, w_hh0, b_ih0, b_hh0,
        w_ih1, w_hh1, b_ih1, b_hh1, w_fc, b_fc, out);
}